// Round 1
// baseline (1556.056 us; speedup 1.0000x reference)
//
#include <hip/hip_runtime.h>
#include <hip/hip_bf16.h>

#define Bsz 2048
#define Tlen 512
#define Hdim 256
#define Vocab 64

typedef __attribute__((ext_vector_type(8))) __bf16 bf16x8;
typedef __attribute__((ext_vector_type(4))) float float4v;

__device__ inline unsigned short f32_bf16(float f) {
    unsigned int u = __float_as_uint(f);
    u += 0x7FFF + ((u >> 16) & 1);   // round-to-nearest-even
    return (unsigned short)(u >> 16);
}

// Build B-operand fragments for the recurrent matmul, K extended to 320:
//   k in [0,256):  B[k][o] = Wh[o][k] = W[o*512 + 256 + k]
//   k in [256,320): B[k][o] = P[k-256][o] = sum_h emb[v][h]*W[o*512+h] + b[o]
// Fragment layout (16x16x32 bf16 B-operand): lane L supplies
//   B[k = ks*32 + (L>>4)*8 + j][o = w*64 + nt*16 + (L&15)], j=0..7 contiguous.
// Linear storage: idx = ((((w*4+nt)*10 + ks)*64 + lane)*8 + j
__global__ void build_frags(const float* __restrict__ emb,
                            const float* __restrict__ W,
                            const float* __restrict__ bias,
                            unsigned short* __restrict__ wt) {
    int idx = blockIdx.x * 256 + threadIdx.x;   // 0..81919
    int j    = idx & 7;
    int lane = (idx >> 3) & 63;
    int fi   = idx >> 9;                        // 0..159
    int ks   = fi % 10;
    int wnt  = fi / 10;                         // 0..15
    int o = (wnt >> 2) * 64 + (wnt & 3) * 16 + (lane & 15);
    int k = ks * 32 + ((lane >> 4) & 3) * 8 + j;
    float val;
    if (k < Hdim) {
        val = W[o * (2 * Hdim) + Hdim + k];
    } else {
        int v = k - Hdim;
        float s = bias[o];
        for (int h = 0; h < Hdim; ++h)
            s += emb[v * Hdim + h] * W[o * (2 * Hdim) + h];
        val = s;
    }
    wt[idx] = f32_bf16(val);
}

// One block = 8 batch rows, full 512-step recurrence, no inter-block sync.
// 4 waves; wave w owns output slice o in [w*64, w*64+64).
// B fragments register-resident (160 VGPR/lane). h exchanged via LDS (bf16),
// double-buffered, one barrier per step. Global stores deferred one step so
// the barrier's vmcnt(0) drain covers them with a full iteration of work.
__global__ __launch_bounds__(256, 1) void rnn_main(
        const int* __restrict__ tokens,
        const float* __restrict__ h0,
        const unsigned short* __restrict__ wt,
        float* __restrict__ out) {
    __shared__ int tok_lds[8 * 513];                 // stride 513: conflict-free
    __shared__ unsigned short hb[2][8 * 264];        // stride 264: 2-way max (free)

    const int tid  = threadIdx.x;
    const int lane = tid & 63;
    const int w    = tid >> 6;          // wave 0..3
    const int lm   = lane & 15;         // A: m index / C: col index
    const int lg   = lane >> 4;         // lane group 0..3
    const int b_base = blockIdx.x * 8;
    const int o_base = w * 64;

    // stage tokens for our 8 rows (coalesced)
    for (int e = 0; e < 16; ++e) {
        int idx = e * 256 + tid;        // 0..4095
        int m = idx >> 9, t = idx & 511;
        tok_lds[m * 513 + t] = tokens[(b_base + m) * Tlen + t];
    }
    // stage h0 -> hb[0] as bf16
    for (int e = 0; e < 8; ++e) {
        int idx = e * 256 + tid;        // 0..2047
        int m = idx >> 8, c = idx & 255;
        hb[0][m * 264 + c] = f32_bf16(h0[(b_base + m) * Hdim + c]);
    }

    // load register-resident B fragments (one-time, coalesced b128)
    bf16x8 bfr[4][10];
    const bf16x8* wp = (const bf16x8*)wt;
#pragma unroll
    for (int nt = 0; nt < 4; ++nt)
#pragma unroll
        for (int ks = 0; ks < 10; ++ks)
            bfr[nt][ks] = wp[(((w * 4 + nt) * 10 + ks) * 64) + lane];

    float pv[4][4];   // previous step's sigmoid outputs (deferred store)

#pragma unroll 2
    for (int t = 0; t < Tlen; ++t) {
        const int cur = t & 1;
        const int nxt = cur ^ 1;
        __syncthreads();   // hb[cur] ready; prior epoch's reads complete

        // deferred global store of step t-1 (max distance to next barrier)
        if (t > 0 && lg < 2) {
#pragma unroll
            for (int r = 0; r < 4; ++r) {
                int row = lg * 4 + r;
                long off = ((long)(t - 1) * Bsz + (b_base + row)) * Hdim;
#pragma unroll
                for (int nt = 0; nt < 4; ++nt)
                    out[off + o_base + nt * 16 + lm] = pv[nt][r];
            }
        }

        // A fragments from LDS (rows 8..15 are padding: alias rows 0..7)
        bf16x8 a[10];
        const unsigned short* hrow = &hb[cur][(lm & 7) * 264];
#pragma unroll
        for (int ks = 0; ks < 8; ++ks)
            a[ks] = *(const bf16x8*)(hrow + ks * 32 + lg * 8);

        // one-hot K-extension selects P[tok] inside the MFMA
        int tok = tok_lds[(lm & 7) * 513 + t];
        {
            bf16x8 a8, a9;
#pragma unroll
            for (int j = 0; j < 8; ++j) {
                int v0 = lg * 8 + j;
                a8[j] = (v0 == tok)      ? (__bf16)1.0f : (__bf16)0.0f;
                a9[j] = (v0 + 32 == tok) ? (__bf16)1.0f : (__bf16)0.0f;
            }
            a[8] = a8;
            a[9] = a9;
        }

        // 4 independent accumulator chains, ks-outer for ILP
        float4v acc[4];
#pragma unroll
        for (int nt = 0; nt < 4; ++nt) {
            float4v z = {0.f, 0.f, 0.f, 0.f};
            acc[nt] = z;
        }
#pragma unroll
        for (int ks = 0; ks < 10; ++ks)
#pragma unroll
            for (int nt = 0; nt < 4; ++nt)
                acc[nt] = __builtin_amdgcn_mfma_f32_16x16x32_bf16(
                    a[ks], bfr[nt][ks], acc[nt], 0, 0, 0);

        // epilogue: sigmoid, stash fp32 for deferred store, bf16 -> hb[nxt]
#pragma unroll
        for (int nt = 0; nt < 4; ++nt) {
#pragma unroll
            for (int r = 0; r < 4; ++r) {
                float x = acc[nt][r];
                float s = 1.0f / (1.0f + __expf(-x));
                pv[nt][r] = s;
                int row = lg * 4 + r;
                if (row < 8)
                    hb[nxt][row * 264 + o_base + nt * 16 + lm] = f32_bf16(s);
            }
        }
    }

    // tail: store step T-1
    if (lg < 2) {
#pragma unroll
        for (int r = 0; r < 4; ++r) {
            int row = lg * 4 + r;
            long off = ((long)(Tlen - 1) * Bsz + (b_base + row)) * Hdim;
#pragma unroll
            for (int nt = 0; nt < 4; ++nt)
                out[off + o_base + nt * 16 + lm] = pv[nt][r];
        }
    }
}

extern "C" void kernel_launch(void* const* d_in, const int* in_sizes, int n_in,
                              void* d_out, int out_size, void* d_ws, size_t ws_size,
                              hipStream_t stream) {
    const int*   tokens = (const int*)d_in[0];
    const float* h0     = (const float*)d_in[1];
    const float* emb    = (const float*)d_in[2];
    const float* W      = (const float*)d_in[3];
    const float* b      = (const float*)d_in[4];
    unsigned short* wt  = (unsigned short*)d_ws;   // 81920 bf16 = 160 KB

    build_frags<<<320, 256, 0, stream>>>(emb, W, b, wt);
    rnn_main<<<256, 256, 0, stream>>>(tokens, h0, wt, (float*)d_out);
}